// Round 18
// baseline (510.014 us; speedup 1.0000x reference)
//
#include <hip/hip_runtime.h>

#define MDIM 8192   // B*S
#define KDIM 4096   // DIN
#define NDIM 11008  // DOUT

#define NBLK_W 1024

typedef float f32x4 __attribute__((ext_vector_type(4)));
typedef int   i32x4 __attribute__((ext_vector_type(4)));
typedef char  c4    __attribute__((ext_vector_type(4)));

#define GAS __attribute__((address_space(1)))
#define LAS __attribute__((address_space(3)))

// --- Kernel 1 (merged): blocks 0..8191 = x fp32->i8 per-row; 8192..9215 = W sign ---
__global__ __launch_bounds__(256) void k_convert(const float* __restrict__ x,
                                                 char* __restrict__ xq,
                                                 float* __restrict__ sx,
                                                 const float* __restrict__ w,
                                                 char* __restrict__ wq,
                                                 float* __restrict__ partials) {
  const int t = (int)threadIdx.x;
  if ((int)blockIdx.x < MDIM) {
    // ---- x row conversion: s_x[row] = max|x[row,:]|/127 ----
    const int row = blockIdx.x;
    const float* xr = x + (size_t)row * KDIM;
    f32x4 v[4];
    float mx = 0.f;
    #pragma unroll
    for (int j = 0; j < 4; ++j) {
      v[j] = *(const f32x4*)(xr + j * 1024 + t * 4);
      mx = fmaxf(mx, fmaxf(fmaxf(fabsf(v[j].x), fabsf(v[j].y)),
                           fmaxf(fabsf(v[j].z), fabsf(v[j].w))));
    }
    #pragma unroll
    for (int off = 32; off > 0; off >>= 1) mx = fmaxf(mx, __shfl_xor(mx, off, 64));
    __shared__ float red[4];
    __shared__ float bmax;
    if ((t & 63) == 0) red[t >> 6] = mx;
    __syncthreads();
    if (t == 0) {
      float m2 = fmaxf(fmaxf(red[0], red[1]), fmaxf(red[2], red[3]));
      m2 = fmaxf(m2, 1e-20f);
      bmax = m2;
      sx[row] = m2 * (1.f / 127.f);
    }
    __syncthreads();
    const float r = 127.f / bmax;
    #pragma unroll
    for (int j = 0; j < 4; ++j) {
      int a = __float2int_rn(v[j].x * r), b = __float2int_rn(v[j].y * r);
      int c = __float2int_rn(v[j].z * r), d = __float2int_rn(v[j].w * r);
      a = a > 127 ? 127 : (a < -127 ? -127 : a);
      b = b > 127 ? 127 : (b < -127 ? -127 : b);
      c = c > 127 ? 127 : (c < -127 ? -127 : c);
      d = d > 127 ? 127 : (d < -127 ? -127 : d);
      c4 q; q.x = (char)a; q.y = (char)b; q.z = (char)c; q.w = (char)d;
      *(c4*)(xq + (size_t)row * KDIM + j * 1024 + t * 4) = q;
    }
  } else {
    // ---- W sign conversion + |W| partial reduction ----
    const int vb = (int)blockIdx.x - MDIM;     // 0..NBLK_W-1
    const int n4 = (NDIM * KDIM) / 4;
    const int stride = NBLK_W * 256;
    float s = 0.f;
    for (int i = vb * 256 + t; i < n4; i += stride) {
      f32x4 v = ((const f32x4*)w)[i];
      s += fabsf(v.x) + fabsf(v.y) + fabsf(v.z) + fabsf(v.w);
      c4 q;
      q.x = v.x > 0.f ? 1 : (v.x < 0.f ? -1 : 0);
      q.y = v.y > 0.f ? 1 : (v.y < 0.f ? -1 : 0);
      q.z = v.z > 0.f ? 1 : (v.z < 0.f ? -1 : 0);
      q.w = v.w > 0.f ? 1 : (v.w < 0.f ? -1 : 0);
      ((c4*)wq)[i] = q;
    }
    #pragma unroll
    for (int off = 32; off > 0; off >>= 1) s += __shfl_down(s, off, 64);
    __shared__ float redw[4];
    if ((t & 63) == 0) redw[t >> 6] = s;
    __syncthreads();
    if (t == 0) partials[vb] = redw[0] + redw[1] + redw[2] + redw[3];
  }
}

// --- Kernel 2: deterministic final reduction -> scale_w = mean|W| ---
__global__ __launch_bounds__(256) void k_scale(const float* __restrict__ partials,
                                               float* __restrict__ scale) {
  float s = 0.f;
  for (int i = threadIdx.x; i < NBLK_W; i += 256) s += partials[i];
  #pragma unroll
  for (int off = 32; off > 0; off >>= 1) s += __shfl_down(s, off, 64);
  __shared__ float red[4];
  if ((threadIdx.x & 63) == 0) red[threadIdx.x >> 6] = s;
  __syncthreads();
  if (threadIdx.x == 0)
    *scale = (red[0] + red[1] + red[2] + red[3]) / (float)((size_t)NDIM * KDIM);
}

// --- Kernel 3: 128x256 i8 GEMM (16x16x64), 2 blk/CU, 3-buffer, 2-PHASE K-tiles ---
// C[m][n] = scale_w * sx[m] * (sum_k xq[m][k]*wq[n][k]) + bias[n]
// vs r17 (417us GEMM, 4 phases/K-tile = 256 barriers/block ~15-20% overhead):
// merge to 2 phases/K-tile (128 barriers). Deep-ledger property preserved:
//   P0: 8 MFMA (afL x bq01,bq23); load afH(bc); stage{A,Bh0,Bh1}(bs); VM(3); BAR
//   P1: 8 MFMA (afH x bq01,bq23); load afL(bn)+bq01(bn)+bq23(bn); BAR
// Ledger: at P0-end outstanding = bn{3, staged i-1.P0} + bs{3, this P0} = 6 ->
//   VM(3) retires bn fully (age 2 long-phases ~1460cyc >= HBM lat) before P1's
//   bn reads. Never 0 in-loop. Prologue: 6 stages + VM(3) retires b0.
// WAR: bs(i)=bc(i-1); bc(i-1)'s last consumption = i-1.P1 MFMAs (lgkm-waited
//   before issue) -> all reads complete when any wave passes i-1.P1's BAR;
//   stage issues i.P0 post-BAR. bq reload @P1 WAR-pinned (SB0) after H-MFMAs;
//   af reload @P0/P1 WAR-pinned after the MFMAs consuming the old half.
// Everything else = r17 byte-wise: 16x16x64 i8, frag layout + 3-bit swizzle
// (0 conflicts), supertile grid (FETCH ~349MB), 3x24KB buffers (72KB, 2blk/CU),
// regs ~56+64acc, VM never counts other VMEM (no spill at this pressure).

#define BAR()  __builtin_amdgcn_s_barrier()
#define SB0()  __builtin_amdgcn_sched_barrier(0)
#define PRIO1() __builtin_amdgcn_s_setprio(1)
#define PRIO0() __builtin_amdgcn_s_setprio(0)
#define VM(N)  asm volatile("s_waitcnt vmcnt(" #N ")" ::: "memory")

// One 8KB half-tile: 128 rows x 64 B; GROWB = global row base; LDSOFF runtime
#define STAGE(GP, GROWB, LDSOFF, KT) do {                                             \
  const char* _s = (GP) + (size_t)((GROWB) + srow) * KDIM + (KT)*64 + scol;           \
  char* _d = lds + (LDSOFF) + tid*16;                                                 \
  __builtin_amdgcn_global_load_lds((const GAS unsigned int*)_s,                       \
                                   (LAS unsigned int*)_d, 16, 0, 0);                  \
} while (0)

// B frag pair: DST[ni] covers output cols wn*64 + NH*32 + ni*16 + l15
#define LOAD_B2(DST, BASE, NH)                                                        \
  _Pragma("unroll") for (int ni = 0; ni < 2; ++ni)                                    \
    DST[ni] = *(const i32x4*)&lds[(BASE) + 8192 + bWOff + (NH)*2048 + ni*1024         \
                                  + rowoff + rcol];

// A frag pair: DST[mi] covers output rows wm*64 + MH*32 + mi*16 + l15
#define LOAD_A2(DST, BASE, MH)                                                        \
  _Pragma("unroll") for (int mi = 0; mi < 2; ++mi)                                    \
    DST[mi] = *(const i32x4*)&lds[(BASE) + aWOff + (MH)*2048 + mi*1024                \
                                  + rowoff + rcol];

// 4 MFMA (16x16x64 i8): 2 mi x 2 ni -> acc[MB+mi][NB+ni]
#define MFMA4(AF, MB, BQ, NB)                                                         \
  _Pragma("unroll") for (int mi = 0; mi < 2; ++mi)                                    \
  _Pragma("unroll") for (int ni = 0; ni < 2; ++ni)                                    \
    acc[(MB)+mi][(NB)+ni] = __builtin_amdgcn_mfma_i32_16x16x64_i8(                    \
        AF[mi], BQ[ni], acc[(MB)+mi][(NB)+ni], 0, 0, 0);

__global__ __launch_bounds__(512, 4) void k_gemm256(const char* __restrict__ A,
                                                    const char* __restrict__ B,
                                                    const float* __restrict__ bias,
                                                    const float* __restrict__ sx,
                                                    const float* __restrict__ scale_p,
                                                    float* __restrict__ C) {
  extern __shared__ char lds[];

  const int nTn = NDIM / 256;                  // 43
  const int nwg = (MDIM / 128) * nTn;          // 2752 (== 0 mod 8)
  int wg = (int)blockIdx.x;
  wg = (wg & 7) * (nwg / 8) + (wg >> 3);       // XCD-aware swizzle (bijective)
  // 8x8 super-tile order within each XCD band (L2 panel reuse; FETCH ~349MB)
  const int band = wg / (nTn * 8);             // 0..7
  const int rem  = wg % (nTn * 8);             // 0..343
  const int tn   = rem >> 3;                   // 0..42
  const int tm   = band * 8 + (rem & 7);       // 0..63

  const int tid  = (int)threadIdx.x;
  const int lane = tid & 63;
  const int wave = tid >> 6;                   // 0..7
  const int wm   = wave >> 2;                  // 0..1  (M)
  const int wn   = wave & 3;                   // 0..3  (N)
  const int l15  = lane & 15;

  // read-side (r13/r15/r17-verified): row = l15 (+16-mults), byte col swizzled
  const int rowoff = l15 * 64;
  const int rcol = ((lane >> 4) << 4) ^ (((l15 >> 1) & 3) << 4);
  // stage-side (verified involution): linear LDS dest; pre-swizzled global col
  const int srow = tid >> 2;                   // 0..127
  const int scol = ((tid & 3) << 4) ^ (((tid >> 3) & 3) << 4);

  const int aWOff = wm * 4096;                 // this wave's 64 A-rows (bytes)
  const int bWOff = wn * 4096;                 // this wave's 64 B-rows (bytes)
  const int aRow = tm * 128;
  const int bRow = tn * 256;

  i32x4 acc[4][4];
  #pragma unroll
  for (int i = 0; i < 4; ++i)
    #pragma unroll
    for (int j = 0; j < 4; ++j) acc[i][j] = i32x4{0, 0, 0, 0};

  i32x4 af[2], bq01[2], bq23[2];

  int b_c = 0, b_n = 24576, b_s = 49152;       // compute / next / stage bases

  // ---- prologue: b0{A,Bh0,Bh1}<-K0; b1{A,Bh0,Bh1}<-K1; VM(3) retires b0 ----
  STAGE(A, aRow,       0,             0);
  STAGE(B, bRow,       8192,          0);
  STAGE(B, bRow + 128, 16384,         0);
  STAGE(A, aRow,       24576,         1);
  STAGE(B, bRow,       24576 + 8192,  1);
  STAGE(B, bRow + 128, 24576 + 16384, 1);
  VM(3);
  SB0();
  BAR();
  LOAD_A2(af, 0, 0); LOAD_B2(bq01, 0, 0); LOAD_B2(bq23, 0, 1);  // K0 operands

  #pragma unroll 1
  for (int i = 0; i < 64; ++i) {
    const int kS = (i + 2 > 63) ? 63 : i + 2;  // clamped tail (idempotent dup)
    // P0: 8 MFMA (afL x bq01,bq23)@bc; load afH(bc); stage{A,Bh0,Bh1}(bs)<-kS;
    //     VM(3) retires bn (age 2 long-phases)
    PRIO1(); MFMA4(af, 0, bq01, 0); MFMA4(af, 0, bq23, 2); PRIO0(); SB0();
    LOAD_A2(af, b_c, 1);
    STAGE(A, aRow,       b_s,         kS);
    STAGE(B, bRow,       b_s + 8192,  kS);
    STAGE(B, bRow + 128, b_s + 16384, kS);
    VM(3); SB0();
    BAR();
    // P1: 8 MFMA (afH x bq01,bq23); load afL(bn)+bq01(bn)+bq23(bn) for next P0
    PRIO1(); MFMA4(af, 2, bq01, 0); MFMA4(af, 2, bq23, 2); PRIO0(); SB0();
    LOAD_A2(af, b_n, 0); LOAD_B2(bq01, b_n, 0); LOAD_B2(bq23, b_n, 1);
    BAR();
    // rotate buffers
    const int t = b_c; b_c = b_n; b_n = b_s; b_s = t;
  }

  VM(0);  // drain tail dup-stages before epilogue

  const float sc = *scale_p;
  float bv[4];
  #pragma unroll
  for (int ni = 0; ni < 4; ++ni) bv[ni] = bias[tn * 256 + wn * 64 + ni * 16 + l15];

  // C/D layout (dtype-independent): col = lane&15, row = (lane>>4)*4 + reg
  #pragma unroll
  for (int mi = 0; mi < 4; ++mi) {
    #pragma unroll
    for (int r = 0; r < 4; ++r) {
      const int m = tm * 128 + wm * 64 + mi * 16 + (lane >> 4) * 4 + r;
      const float srow_scale = sc * sx[m];
      float* crow = C + (size_t)m * NDIM + tn * 256 + wn * 64;
      #pragma unroll
      for (int ni = 0; ni < 4; ++ni)
        crow[ni * 16 + l15] = srow_scale * (float)acc[mi][ni][r] + bv[ni];
    }
  }
}

extern "C" void kernel_launch(void* const* d_in, const int* in_sizes, int n_in,
                              void* d_out, int out_size, void* d_ws, size_t ws_size,
                              hipStream_t stream) {
  const float* x = (const float*)d_in[0];
  const float* w = (const float*)d_in[1];
  const float* bias = (const float*)d_in[2];
  float* out = (float*)d_out;

  char* ws = (char*)d_ws;
  const size_t XQ_BYTES = (size_t)MDIM * KDIM;   // 33,554,432
  const size_t WQ_BYTES = (size_t)NDIM * KDIM;   // 45,088,768
  char* xq = ws;
  char* wq = ws + XQ_BYTES;
  float* sx = (float*)(ws + XQ_BYTES + WQ_BYTES);
  float* partials = sx + MDIM;
  float* scale = partials + NBLK_W;

  k_convert<<<MDIM + NBLK_W, 256, 0, stream>>>(x, xq, sx, w, wq, partials);
  k_scale<<<1, 256, 0, stream>>>(partials, scale);

  (void)hipFuncSetAttribute((const void*)k_gemm256,
                            hipFuncAttributeMaxDynamicSharedMemorySize, 73728);
  const int grid = (MDIM / 128) * (NDIM / 256);  // 2752
  k_gemm256<<<grid, 512, 73728, stream>>>(xq, wq, bias, sx, scale, out);
}